// Round 6
// baseline (124.584 us; speedup 1.0000x reference)
//
#include <hip/hip_runtime.h>
#include <math.h>

#define MM 64
#define NA 24
#define NP 276
#define NT 6000
#define QC 0.22360679774997896f
#define EXPC 0.01666666666666667f  // 5/(3*sig^2), sig=10

// k2 tiles: 6048 = 112 chunks x 54 k, single staging round, 4 blocks/CU
#define G2S   112
#define G2R   54

// ---- workspace layout (float offsets) ----
#define OFF_WT   0           // wT[t][m] 6048*64 (rows 6000..6047 zeroed by k_pre)
#define OFF_ET   387072      // eT[t][m] 6048*64
#define OFF_SLAB 774144      // slab[cid][mat][p][m] 112*2*276*64 (k2 partials)
#define OFF_ESP  4730880     // esP[tile][m] 375*64
#define OFF_SWP  4754880     // swP[tile][m] 375*64
#define OFF_XS2  4778880     // xsT2[half][p][ml] 2*276*32
#define OFF_UU   4796544     // 64
#define OFF_F    4796608     // F[mat][p][m] 2*276*64 (k_red output)
#define SLABSTRIDE 35328     // 2*276*64 (per-cid stride)

__device__ __forceinline__ void p2ij(int p, int& i, int& j) {
  int ii = (int)((1.0f + sqrtf(1.0f + 8.0f * (float)p)) * 0.5f);
  while (ii * (ii - 1) / 2 > p) ii--;
  while ((ii + 1) * ii / 2 <= p) ii++;
  j = p - ii * (ii - 1) / 2;
  i = ii;
}

// ---------- kernel 0: xsT2 + uu, 64 blocks ----------
__global__ __launch_bounds__(256) void k_pre(const float* __restrict__ Rs,
                                             float* __restrict__ ws) {
  const int tid = threadIdx.x;
  const int m = blockIdx.x;
  // blocks 0,1 also zero the wT/eT tail rows (6000..6047)
  if (m < 2) {
    float* tz = ws + (m ? OFF_ET : OFF_WT) + (size_t)NT * 64;
    for (int z = tid; z < 48 * 64; z += 256) tz[z] = 0.f;
  }
  __shared__ float sR[NA * 3];
  __shared__ float sAcc[4];
  if (tid < NA * 3) sR[tid] = Rs[m * NA * 3 + tid];
  __syncthreads();
  float acc = 0.f;
  for (int p = tid; p < NP; p += 256) {
    int i, j;
    p2ij(p, i, j);
    const float dx = sR[i * 3 + 0] - sR[j * 3 + 0];
    const float dy = sR[i * 3 + 1] - sR[j * 3 + 1];
    const float dz = sR[i * 3 + 2] - sR[j * 3 + 2];
    const float u = 1.0f / sqrtf(dx * dx + dy * dy + dz * dz);
    ws[OFF_XS2 + (size_t)(m >> 5) * NP * 32 + p * 32 + (m & 31)] = u;
    acc = fmaf(u, u, acc);
  }
#pragma unroll
  for (int off = 32; off; off >>= 1) acc += __shfl_down(acc, off);
  if ((tid & 63) == 0) sAcc[tid >> 6] = acc;
  __syncthreads();
  if (tid == 0) ws[OFF_UU + m] = sAcc[0] + sAcc[1] + sAcc[2] + sAcc[3];
}

// ---------- kernel 1: GEMM1 + in-block stats + elementwise; 4-way K-split, 4m x 2t ----------
// grid (375 t-tiles, 2 m-halves); block 256 = 4 waves.
// Wave w: k-range [68w, 68w+68) (wave 3: +72). Lane: mg=lane&7 (4m), tg=lane>>3 (2t).
#define K1SUB(A, vb0, vb1, jb0, jb1)                                               \
  av0[0] = fmaf(A.x, vb0, av0[0]); av0[1] = fmaf(A.y, vb0, av0[1]);                \
  av0[2] = fmaf(A.z, vb0, av0[2]); av0[3] = fmaf(A.w, vb0, av0[3]);                \
  av1[0] = fmaf(A.x, vb1, av1[0]); av1[1] = fmaf(A.y, vb1, av1[1]);                \
  av1[2] = fmaf(A.z, vb1, av1[2]); av1[3] = fmaf(A.w, vb1, av1[3]);                \
  aj0[0] = fmaf(A.x, jb0, aj0[0]); aj0[1] = fmaf(A.y, jb0, aj0[1]);                \
  aj0[2] = fmaf(A.z, jb0, aj0[2]); aj0[3] = fmaf(A.w, jb0, aj0[3]);                \
  aj1[0] = fmaf(A.x, jb1, aj1[0]); aj1[1] = fmaf(A.y, jb1, aj1[1]);                \
  aj1[2] = fmaf(A.z, jb1, aj1[2]); aj1[3] = fmaf(A.w, jb1, aj1[3]);

__global__ __launch_bounds__(256, 2) void k1(const float* __restrict__ xt,
                                             const float* __restrict__ Ja,
                                             float* __restrict__ ws) {
  __shared__ __align__(16) float Bv[16 * NP];   // flat copy of xt tile
  __shared__ __align__(16) float Bj[16 * NP];   // flat copy of Ja tile
  __shared__ __align__(16) float As[NP * 32];   // xsT2 half [p][ml]; reused as red[3][16][64]
  __shared__ float sVV[16], sC1[16];
  const int tid = threadIdx.x;
  const int t0 = blockIdx.x * 16;
  const int m0 = blockIdx.y * 32;
  const int w = tid >> 6;
  const int lane = tid & 63;
  const int mg = lane & 7;     // m-quad: m = m0 + 4*mg .. +3
  const int tg = lane >> 3;    // t-pair: t = t0 + 2*tg + {0,1}

  const float4 uu4 = *(const float4*)(ws + OFF_UU + m0 + 4 * mg);

  // stage: pure linear float4 copies
  {
    const float4* xs4 = (const float4*)(xt + (size_t)t0 * NP);
    const float4* js4 = (const float4*)(Ja + (size_t)t0 * NP);
    const float4* as4 = (const float4*)(ws + OFF_XS2 + (size_t)blockIdx.y * NP * 32);
    float4* bv4 = (float4*)Bv;
    float4* bj4 = (float4*)Bj;
    float4* a4  = (float4*)As;
    for (int i = tid; i < 16 * NP / 4; i += 256) { bv4[i] = xs4[i]; bj4[i] = js4[i]; }
    for (int i = tid; i < NP * 32 / 4; i += 256) a4[i] = as4[i];
  }
  __syncthreads();

  // in-block stats from staged tiles: vv[t], c1[t] (16 lanes per t)
  {
    const int tl = tid >> 4;
    const int l16 = tid & 15;
    const float* bvr = Bv + tl * NP;
    const float* bjr = Bj + tl * NP;
    float a = 0.f, b = 0.f;
    for (int k = l16; k < NP; k += 16) {
      const float v = bvr[k];
      a = fmaf(v, v, a);
      b = fmaf(v, bjr[k], b);
    }
#pragma unroll
    for (int off = 8; off; off >>= 1) {
      a += __shfl_down(a, off, 16);
      b += __shfl_down(b, off, 16);
    }
    if (l16 == 0) { sVV[tl] = a; sC1[tl] = b; }
  }

  float av0[4] = {0.f, 0.f, 0.f, 0.f}, av1[4] = {0.f, 0.f, 0.f, 0.f};
  float aj0[4] = {0.f, 0.f, 0.f, 0.f}, aj1[4] = {0.f, 0.f, 0.f, 0.f};
  const float* BvR0 = Bv + (2 * tg + 0) * NP;
  const float* BvR1 = Bv + (2 * tg + 1) * NP;
  const float* BjR0 = Bj + (2 * tg + 0) * NP;
  const float* BjR1 = Bj + (2 * tg + 1) * NP;
  const float* Ac = As + 4 * mg;
  const int kbeg = w * 68;
  const int kend = (w == 3) ? NP : (kbeg + 68);
#pragma unroll 2
  for (int k = kbeg; k < kend; k += 4) {
    const float4 a0 = *(const float4*)(Ac + (k + 0) * 32);
    const float4 a1 = *(const float4*)(Ac + (k + 1) * 32);
    const float4 a2 = *(const float4*)(Ac + (k + 2) * 32);
    const float4 a3 = *(const float4*)(Ac + (k + 3) * 32);
    const float4 bv0 = *(const float4*)(BvR0 + k);
    const float4 bv1 = *(const float4*)(BvR1 + k);
    const float4 bj0 = *(const float4*)(BjR0 + k);
    const float4 bj1 = *(const float4*)(BjR1 + k);
    K1SUB(a0, bv0.x, bv1.x, bj0.x, bj1.x)
    K1SUB(a1, bv0.y, bv1.y, bj0.y, bj1.y)
    K1SUB(a2, bv0.z, bv1.z, bj0.z, bj1.z)
    K1SUB(a3, bv0.w, bv1.w, bj0.w, bj1.w)
  }
  __syncthreads();   // all waves done reading As/Bv/Bj

  if (w > 0) {
    float* red = As + (size_t)(w - 1) * 16 * 64;   // 3*1024 <= 8832 floats ok
#pragma unroll
    for (int q = 0; q < 4; q++) {
      red[(q + 0) * 64 + lane]  = av0[q];
      red[(q + 4) * 64 + lane]  = av1[q];
      red[(q + 8) * 64 + lane]  = aj0[q];
      red[(q + 12) * 64 + lane] = aj1[q];
    }
  }
  __syncthreads();
  if (w == 0) {
#pragma unroll
    for (int ww = 0; ww < 3; ww++) {
      const float* red = As + (size_t)ww * 16 * 64;
#pragma unroll
      for (int q = 0; q < 4; q++) {
        av0[q] += red[(q + 0) * 64 + lane];
        av1[q] += red[(q + 4) * 64 + lane];
        aj0[q] += red[(q + 8) * 64 + lane];
        aj1[q] += red[(q + 12) * 64 + lane];
      }
    }
    float es[4] = {0.f, 0.f, 0.f, 0.f}, swv[4] = {0.f, 0.f, 0.f, 0.f};
    const float uum[4] = {uu4.x, uu4.y, uu4.z, uu4.w};
#pragma unroll
    for (int tj = 0; tj < 2; tj++) {
      const float vvt = sVV[2 * tg + tj];
      const float c1t = sC1[2 * tg + tj];
      const float* g1 = tj ? av1 : av0;
      const float* g2 = tj ? aj1 : aj0;
      float wq[4], eq[4];
#pragma unroll
      for (int mi = 0; mi < 4; mi++) {
        const float d2 = fmaxf(uum[mi] - 2.f * g1[mi] + vvt, 0.f);
        const float xd = QC * sqrtf(d2);
        const float dv = QC * (g2[mi] - c1t);
        const float ex = EXPC * __expf(-xd);
        const float e1v = ex * (1.f + xd);
        const float w_ = ex * dv;
        wq[mi] = w_; eq[mi] = e1v;
        es[mi] += e1v * dv; swv[mi] += w_;
      }
      const int t = t0 + 2 * tg + tj;
      *(float4*)(ws + OFF_WT + (size_t)t * 64 + m0 + 4 * mg) = make_float4(wq[0], wq[1], wq[2], wq[3]);
      *(float4*)(ws + OFF_ET + (size_t)t * 64 + m0 + 4 * mg) = make_float4(eq[0], eq[1], eq[2], eq[3]);
    }
    // reduce es/sw over the 8 t-groups (lane bits 3..5)
#pragma unroll
    for (int q = 0; q < 4; q++) {
      es[q] += __shfl_down(es[q], 32); es[q] += __shfl_down(es[q], 16); es[q] += __shfl_down(es[q], 8);
      swv[q] += __shfl_down(swv[q], 32); swv[q] += __shfl_down(swv[q], 16); swv[q] += __shfl_down(swv[q], 8);
    }
    if (lane < 8) {
      *(float4*)(ws + OFF_ESP + (size_t)blockIdx.x * 64 + m0 + 4 * lane) =
          make_float4(es[0], es[1], es[2], es[3]);
      *(float4*)(ws + OFF_SWP + (size_t)blockIdx.x * 64 + m0 + 4 * lane) =
          make_float4(swv[0], swv[1], swv[2], swv[3]);
    }
  }
}

// ---------- kernel 2: GEMM2, 4-way K-split, 4m x 4p, 54-k chunks, 4 blocks/CU ----------
// grid (18 p-tiles x 112 k-chunks); block 256 = 4 waves.
// Flat LDS S: Aw = S[0..3455], Ae = S[3456..6911], Bvj = S[6912..8639] (float2[54][16]).
// Reduce regions (post-barrier alias): red[w-1] = S + (w-1)*2048, 3*2048 = 6144 <= 8640. [r5 bug: Bvj(1728f) < 2048f overflowed]
__global__ __launch_bounds__(256, 4) void k2(const float* __restrict__ xt,
                                             const float* __restrict__ Ja,
                                             float* __restrict__ ws) {
  __shared__ __align__(16) float S[G2R * 64 * 2 + G2R * 32];   // 8640 floats = 34560 B
  float* Aw = S;
  float* Ae = S + G2R * 64;
  float2* Bvj = (float2*)(S + 2 * G2R * 64);   // [k][16] interleaved (v,j)
  const int tid = threadIdx.x;
  const int p0 = blockIdx.x * 16;
  const int cid = blockIdx.y;
  const int k0 = cid * G2R;
  const int validp = (NP - p0 < 16) ? (NP - p0) : 16;
  const int w = tid >> 6;
  const int lane = tid & 63;
  const int mg = lane & 15;   // m-quad: m = 4*mg .. +3
  const int pg = lane >> 4;   // p-quad: p = p0 + 4*pg .. +3

  // stage A: contiguous memcpy of wT/eT rows k0..k0+53 (tail rows pre-zeroed)
  {
    const float4* aws = (const float4*)(ws + OFF_WT + (size_t)k0 * 64);
    const float4* aes = (const float4*)(ws + OFF_ET + (size_t)k0 * 64);
    float4* aw4 = (float4*)Aw;
    float4* ae4 = (float4*)Ae;
    for (int idx = tid; idx < G2R * 16; idx += 256) { aw4[idx] = aws[idx]; ae4[idx] = aes[idx]; }
  }
  // stage B: (xt,Ja) interleaved [k][p-local]
  if (tid < G2R * 4) {
    const int k = tid >> 2;
    const int pq = (tid & 3) * 4;
    const int t = k0 + k;
    float4 v = make_float4(0.f, 0.f, 0.f, 0.f), j = v;
    if (pq < validp && t < NT) {
      v = *(const float4*)(xt + (size_t)t * NP + p0 + pq);
      j = *(const float4*)(Ja + (size_t)t * NP + p0 + pq);
    }
    *(float4*)&Bvj[k * 16 + pq]     = make_float4(v.x, j.x, v.y, j.y);
    *(float4*)&Bvj[k * 16 + pq + 2] = make_float4(v.z, j.z, v.w, j.w);
  }
  __syncthreads();

  float f1[4][4] = {{0.f}}, f2[4][4] = {{0.f}};
  const float* AwL = Aw + 4 * mg;
  const float* AeL = Ae + 4 * mg;
  const int kb = (w * G2R) >> 2;
  const int ke = ((w + 1) * G2R) >> 2;
#pragma unroll 2
  for (int k = kb; k < ke; ++k) {
    const float4 aw = *(const float4*)(AwL + (size_t)k * 64);
    const float4 ae = *(const float4*)(AeL + (size_t)k * 64);
    const float4 b01 = *(const float4*)&Bvj[k * 16 + 4 * pg];
    const float4 b23 = *(const float4*)&Bvj[k * 16 + 4 * pg + 2];
    const float vb[4] = {b01.x, b01.z, b23.x, b23.z};
    const float jb[4] = {b01.y, b01.w, b23.y, b23.w};
    const float aww[4] = {aw.x, aw.y, aw.z, aw.w};
    const float aee[4] = {ae.x, ae.y, ae.z, ae.w};
#pragma unroll
    for (int mi = 0; mi < 4; mi++)
#pragma unroll
      for (int pj = 0; pj < 4; pj++) {
        f1[mi][pj] = fmaf(aww[mi], vb[pj], f1[mi][pj]);
        f2[mi][pj] = fmaf(aee[mi], jb[pj], f2[mi][pj]);
      }
  }
  __syncthreads();   // all waves done reading Aw/Ae/Bvj

  if (w > 0) {
    float* red = S + (size_t)(w - 1) * 2048;
#pragma unroll
    for (int mi = 0; mi < 4; mi++)
#pragma unroll
      for (int pj = 0; pj < 4; pj++) {
        red[(mi * 4 + pj) * 64 + lane]      = f1[mi][pj];
        red[(16 + mi * 4 + pj) * 64 + lane] = f2[mi][pj];
      }
  }
  __syncthreads();
  if (w == 0) {
#pragma unroll
    for (int ww = 0; ww < 3; ww++) {
      const float* red = S + (size_t)ww * 2048;
#pragma unroll
      for (int mi = 0; mi < 4; mi++)
#pragma unroll
        for (int pj = 0; pj < 4; pj++) {
          f1[mi][pj] += red[(mi * 4 + pj) * 64 + lane];
          f2[mi][pj] += red[(16 + mi * 4 + pj) * 64 + lane];
        }
    }
    float* b1 = ws + OFF_SLAB + (size_t)(cid * 2 + 0) * NP * 64;
    float* b2 = ws + OFF_SLAB + (size_t)(cid * 2 + 1) * NP * 64;
#pragma unroll
    for (int pj = 0; pj < 4; pj++) {
      const int pl = 4 * pg + pj;
      if (pl < validp) {
        const int p = p0 + pl;
        *(float4*)(b1 + (size_t)p * 64 + 4 * mg) =
            make_float4(f1[0][pj], f1[1][pj], f1[2][pj], f1[3][pj]);
        *(float4*)(b2 + (size_t)p * 64 + 4 * mg) =
            make_float4(f2[0][pj], f2[1][pj], f2[2][pj], f2[3][pj]);
      }
    }
  }
}

// ---------- kernel 2.5: slab reduce, fully coalesced, thread-per-output ----------
__global__ __launch_bounds__(256) void k_red(float* __restrict__ ws) {
  const int inner = blockIdx.x * 256 + threadIdx.x;   // 138*256 = 35328 exactly
  const float* src = ws + OFF_SLAB + inner;
  float s = 0.f;
#pragma unroll 4
  for (int cid = 0; cid < G2S; cid++) s += src[(size_t)cid * SLABSTRIDE];
  ws[OFF_F + inner] = s;
}

// ---------- kernel 3: finalize (Es, forces) ----------
__global__ __launch_bounds__(320) void k3(const float* __restrict__ Rs,
                                          const float* __restrict__ ws,
                                          float* __restrict__ out) {
  const int m = blockIdx.x;
  const int tid = threadIdx.x;
  __shared__ float fx[NP];
  __shared__ float sR[NA * 3];
  __shared__ float sEsw[5], sSww[5];
  __shared__ float sTot[2];
  if (tid < NA * 3) sR[tid] = Rs[m * NA * 3 + tid];

  float aE = 0.f, aS = 0.f;
  for (int tt = tid; tt < 375; tt += 320) {
    aE += ws[OFF_ESP + (size_t)tt * 64 + m];
    aS += ws[OFF_SWP + (size_t)tt * 64 + m];
  }
#pragma unroll
  for (int off = 32; off; off >>= 1) {
    aE += __shfl_down(aE, off);
    aS += __shfl_down(aS, off);
  }
  if ((tid & 63) == 0) { sEsw[tid >> 6] = aE; sSww[tid >> 6] = aS; }
  __syncthreads();
  if (tid == 0) {
    float e = 0.f, s = 0.f;
#pragma unroll
    for (int w = 0; w < 5; w++) { e += sEsw[w]; s += sSww[w]; }
    sTot[0] = e; sTot[1] = s;
    out[m] = e / QC;  // *STD + C, STD=1, C=0
  }
  __syncthreads();
  const float sw = sTot[1];

  for (int p = tid; p < NP; p += 320) {
    const float f1p = ws[OFF_F + (size_t)0 * NP * 64 + p * 64 + m];
    const float f2  = ws[OFF_F + (size_t)1 * NP * 64 + p * 64 + m];
    const float u = ws[OFF_XS2 + (size_t)(m >> 5) * NP * 32 + p * 32 + (m & 31)];
    const float F1 = QC * (u * sw - f1p);
    fx[p] = (F1 - f2) * u * u * u;
  }
  __syncthreads();

  if (tid < NA * 3) {
    const int a = tid / 3, cc = tid % 3;
    const float ra = sR[a * 3 + cc];
    float acc = 0.f;
    for (int b = 0; b < NA; b++) {
      if (b == a) continue;
      const int i = a > b ? a : b, j = a > b ? b : a;
      const int p = i * (i - 1) / 2 + j;
      acc += (sR[b * 3 + cc] - ra) * fx[p];
    }
    out[MM + m * NA * 3 + tid] = acc;
  }
}

extern "C" void kernel_launch(void* const* d_in, const int* in_sizes, int n_in,
                              void* d_out, int out_size, void* d_ws, size_t ws_size,
                              hipStream_t stream) {
  const float* Rs = (const float*)d_in[0];
  const float* xt = (const float*)d_in[1];
  const float* Ja = (const float*)d_in[2];
  float* out = (float*)d_out;
  float* ws = (float*)d_ws;

  k_pre<<<MM, 256, 0, stream>>>(Rs, ws);
  k1<<<dim3(375, 2), 256, 0, stream>>>(xt, Ja, ws);
  k2<<<dim3(18, G2S), 256, 0, stream>>>(xt, Ja, ws);
  k_red<<<138, 256, 0, stream>>>(ws);
  k3<<<MM, 320, 0, stream>>>(Rs, ws, out);
}

// Round 7
// 118.383 us; speedup vs baseline: 1.0524x; 1.0524x over previous
//
#include <hip/hip_runtime.h>
#include <math.h>

#define MM 64
#define NA 24
#define NP 276
#define NT 6000
#define QC 0.22360679774997896f
#define EXPC 0.01666666666666667f  // 5/(3*sig^2), sig=10

// k2 tiles: 6048 = 56 chunks x 108 k, single staging round, 2 blocks/CU (round-4 proven)
#define G2S   56
#define G2R   108

// ---- workspace layout (float offsets) ----
#define OFF_WT   0           // wT[t][m] 6048*64 (rows 6000..6047 zeroed by k_pre)
#define OFF_ET   387072      // eT[t][m] 6048*64
#define OFF_SLAB 774144      // slab[cid][mat][p][m] 56*2*276*64 (k2 partials)
#define OFF_ESP  2752512     // esP[tile][m] 375*64
#define OFF_SWP  2776512     // swP[tile][m] 375*64
#define OFF_XS2  2800512     // xsT2[half][p][ml] 2*276*32
#define OFF_UU   2818176     // 64
#define OFF_F    2818240     // F[mat][p][m] 2*276*64 (k_red output)
#define SLABSTRIDE 35328     // 2*276*64 (per-cid stride)

__device__ __forceinline__ void p2ij(int p, int& i, int& j) {
  int ii = (int)((1.0f + sqrtf(1.0f + 8.0f * (float)p)) * 0.5f);
  while (ii * (ii - 1) / 2 > p) ii--;
  while ((ii + 1) * ii / 2 <= p) ii++;
  j = p - ii * (ii - 1) / 2;
  i = ii;
}

// ---------- kernel 0: xsT2 + uu, 64 blocks ----------
__global__ __launch_bounds__(256) void k_pre(const float* __restrict__ Rs,
                                             float* __restrict__ ws) {
  const int tid = threadIdx.x;
  const int m = blockIdx.x;
  // blocks 0,1 also zero the wT/eT tail rows (6000..6047)
  if (m < 2) {
    float* tz = ws + (m ? OFF_ET : OFF_WT) + (size_t)NT * 64;
    for (int z = tid; z < 48 * 64; z += 256) tz[z] = 0.f;
  }
  __shared__ float sR[NA * 3];
  __shared__ float sAcc[4];
  if (tid < NA * 3) sR[tid] = Rs[m * NA * 3 + tid];
  __syncthreads();
  float acc = 0.f;
  for (int p = tid; p < NP; p += 256) {
    int i, j;
    p2ij(p, i, j);
    const float dx = sR[i * 3 + 0] - sR[j * 3 + 0];
    const float dy = sR[i * 3 + 1] - sR[j * 3 + 1];
    const float dz = sR[i * 3 + 2] - sR[j * 3 + 2];
    const float u = 1.0f / sqrtf(dx * dx + dy * dy + dz * dz);
    ws[OFF_XS2 + (size_t)(m >> 5) * NP * 32 + p * 32 + (m & 31)] = u;
    acc = fmaf(u, u, acc);
  }
#pragma unroll
  for (int off = 32; off; off >>= 1) acc += __shfl_down(acc, off);
  if ((tid & 63) == 0) sAcc[tid >> 6] = acc;
  __syncthreads();
  if (tid == 0) ws[OFF_UU + m] = sAcc[0] + sAcc[1] + sAcc[2] + sAcc[3];
}

// ---------- kernel 1: GEMM1 + in-block stats + elementwise; 4-way K-split, 4m x 2t ----------
// grid (375 t-tiles, 2 m-halves); block 256 = 4 waves.
// Wave w: k-range [68w, 68w+68) (wave 3: +72). Lane: mg=lane&7 (4m), tg=lane>>3 (2t).
#define K1SUB(A, vb0, vb1, jb0, jb1)                                               \
  av0[0] = fmaf(A.x, vb0, av0[0]); av0[1] = fmaf(A.y, vb0, av0[1]);                \
  av0[2] = fmaf(A.z, vb0, av0[2]); av0[3] = fmaf(A.w, vb0, av0[3]);                \
  av1[0] = fmaf(A.x, vb1, av1[0]); av1[1] = fmaf(A.y, vb1, av1[1]);                \
  av1[2] = fmaf(A.z, vb1, av1[2]); av1[3] = fmaf(A.w, vb1, av1[3]);                \
  aj0[0] = fmaf(A.x, jb0, aj0[0]); aj0[1] = fmaf(A.y, jb0, aj0[1]);                \
  aj0[2] = fmaf(A.z, jb0, aj0[2]); aj0[3] = fmaf(A.w, jb0, aj0[3]);                \
  aj1[0] = fmaf(A.x, jb1, aj1[0]); aj1[1] = fmaf(A.y, jb1, aj1[1]);                \
  aj1[2] = fmaf(A.z, jb1, aj1[2]); aj1[3] = fmaf(A.w, jb1, aj1[3]);

__global__ __launch_bounds__(256, 2) void k1(const float* __restrict__ xt,
                                             const float* __restrict__ Ja,
                                             float* __restrict__ ws) {
  __shared__ __align__(16) float Bv[16 * NP];   // flat copy of xt tile
  __shared__ __align__(16) float Bj[16 * NP];   // flat copy of Ja tile
  __shared__ __align__(16) float As[NP * 32];   // xsT2 half [p][ml]; reused as red[3][16][64]
  __shared__ float sVV[16], sC1[16];
  const int tid = threadIdx.x;
  const int t0 = blockIdx.x * 16;
  const int m0 = blockIdx.y * 32;
  const int w = tid >> 6;
  const int lane = tid & 63;
  const int mg = lane & 7;     // m-quad: m = m0 + 4*mg .. +3
  const int tg = lane >> 3;    // t-pair: t = t0 + 2*tg + {0,1}

  const float4 uu4 = *(const float4*)(ws + OFF_UU + m0 + 4 * mg);

  // stage: pure linear float4 copies
  {
    const float4* xs4 = (const float4*)(xt + (size_t)t0 * NP);
    const float4* js4 = (const float4*)(Ja + (size_t)t0 * NP);
    const float4* as4 = (const float4*)(ws + OFF_XS2 + (size_t)blockIdx.y * NP * 32);
    float4* bv4 = (float4*)Bv;
    float4* bj4 = (float4*)Bj;
    float4* a4  = (float4*)As;
    for (int i = tid; i < 16 * NP / 4; i += 256) { bv4[i] = xs4[i]; bj4[i] = js4[i]; }
    for (int i = tid; i < NP * 32 / 4; i += 256) a4[i] = as4[i];
  }
  __syncthreads();

  // in-block stats from staged tiles: vv[t], c1[t] (16 lanes per t)
  {
    const int tl = tid >> 4;
    const int l16 = tid & 15;
    const float* bvr = Bv + tl * NP;
    const float* bjr = Bj + tl * NP;
    float a = 0.f, b = 0.f;
    for (int k = l16; k < NP; k += 16) {
      const float v = bvr[k];
      a = fmaf(v, v, a);
      b = fmaf(v, bjr[k], b);
    }
#pragma unroll
    for (int off = 8; off; off >>= 1) {
      a += __shfl_down(a, off, 16);
      b += __shfl_down(b, off, 16);
    }
    if (l16 == 0) { sVV[tl] = a; sC1[tl] = b; }
  }

  float av0[4] = {0.f, 0.f, 0.f, 0.f}, av1[4] = {0.f, 0.f, 0.f, 0.f};
  float aj0[4] = {0.f, 0.f, 0.f, 0.f}, aj1[4] = {0.f, 0.f, 0.f, 0.f};
  const float* BvR0 = Bv + (2 * tg + 0) * NP;
  const float* BvR1 = Bv + (2 * tg + 1) * NP;
  const float* BjR0 = Bj + (2 * tg + 0) * NP;
  const float* BjR1 = Bj + (2 * tg + 1) * NP;
  const float* Ac = As + 4 * mg;
  const int kbeg = w * 68;
  const int kend = (w == 3) ? NP : (kbeg + 68);
#pragma unroll 2
  for (int k = kbeg; k < kend; k += 4) {
    const float4 a0 = *(const float4*)(Ac + (k + 0) * 32);
    const float4 a1 = *(const float4*)(Ac + (k + 1) * 32);
    const float4 a2 = *(const float4*)(Ac + (k + 2) * 32);
    const float4 a3 = *(const float4*)(Ac + (k + 3) * 32);
    const float4 bv0 = *(const float4*)(BvR0 + k);
    const float4 bv1 = *(const float4*)(BvR1 + k);
    const float4 bj0 = *(const float4*)(BjR0 + k);
    const float4 bj1 = *(const float4*)(BjR1 + k);
    K1SUB(a0, bv0.x, bv1.x, bj0.x, bj1.x)
    K1SUB(a1, bv0.y, bv1.y, bj0.y, bj1.y)
    K1SUB(a2, bv0.z, bv1.z, bj0.z, bj1.z)
    K1SUB(a3, bv0.w, bv1.w, bj0.w, bj1.w)
  }
  __syncthreads();   // all waves done reading As/Bv/Bj

  if (w > 0) {
    float* red = As + (size_t)(w - 1) * 16 * 64;   // 3*1024 <= 8832 floats ok
#pragma unroll
    for (int q = 0; q < 4; q++) {
      red[(q + 0) * 64 + lane]  = av0[q];
      red[(q + 4) * 64 + lane]  = av1[q];
      red[(q + 8) * 64 + lane]  = aj0[q];
      red[(q + 12) * 64 + lane] = aj1[q];
    }
  }
  __syncthreads();
  if (w == 0) {
#pragma unroll
    for (int ww = 0; ww < 3; ww++) {
      const float* red = As + (size_t)ww * 16 * 64;
#pragma unroll
      for (int q = 0; q < 4; q++) {
        av0[q] += red[(q + 0) * 64 + lane];
        av1[q] += red[(q + 4) * 64 + lane];
        aj0[q] += red[(q + 8) * 64 + lane];
        aj1[q] += red[(q + 12) * 64 + lane];
      }
    }
    float es[4] = {0.f, 0.f, 0.f, 0.f}, swv[4] = {0.f, 0.f, 0.f, 0.f};
    const float uum[4] = {uu4.x, uu4.y, uu4.z, uu4.w};
#pragma unroll
    for (int tj = 0; tj < 2; tj++) {
      const float vvt = sVV[2 * tg + tj];
      const float c1t = sC1[2 * tg + tj];
      const float* g1 = tj ? av1 : av0;
      const float* g2 = tj ? aj1 : aj0;
      float wq[4], eq[4];
#pragma unroll
      for (int mi = 0; mi < 4; mi++) {
        const float d2 = fmaxf(uum[mi] - 2.f * g1[mi] + vvt, 0.f);
        const float xd = QC * sqrtf(d2);
        const float dv = QC * (g2[mi] - c1t);
        const float ex = EXPC * __expf(-xd);
        const float e1v = ex * (1.f + xd);
        const float w_ = ex * dv;
        wq[mi] = w_; eq[mi] = e1v;
        es[mi] += e1v * dv; swv[mi] += w_;
      }
      const int t = t0 + 2 * tg + tj;
      *(float4*)(ws + OFF_WT + (size_t)t * 64 + m0 + 4 * mg) = make_float4(wq[0], wq[1], wq[2], wq[3]);
      *(float4*)(ws + OFF_ET + (size_t)t * 64 + m0 + 4 * mg) = make_float4(eq[0], eq[1], eq[2], eq[3]);
    }
    // reduce es/sw over the 8 t-groups (lane bits 3..5)
#pragma unroll
    for (int q = 0; q < 4; q++) {
      es[q] += __shfl_down(es[q], 32); es[q] += __shfl_down(es[q], 16); es[q] += __shfl_down(es[q], 8);
      swv[q] += __shfl_down(swv[q], 32); swv[q] += __shfl_down(swv[q], 16); swv[q] += __shfl_down(swv[q], 8);
    }
    if (lane < 8) {
      *(float4*)(ws + OFF_ESP + (size_t)blockIdx.x * 64 + m0 + 4 * lane) =
          make_float4(es[0], es[1], es[2], es[3]);
      *(float4*)(ws + OFF_SWP + (size_t)blockIdx.x * 64 + m0 + 4 * lane) =
          make_float4(swv[0], swv[1], swv[2], swv[3]);
    }
  }
}

// ---------- kernel 2: GEMM2, 4-way K-split, 4m x 4p, 108-k chunks, 2 blocks/CU (round-4 proven) ----------
// grid (18 p-tiles x 56 k-chunks); block 256 = 4 waves.
// Wave w: k in [27w, 27w+27). Lane: mg=lane&15 (4m), pg=lane>>4 (4p).
// Reduce regions: Aw (6912f), Ae (6912f), Bvj (3456f) — each >= 2048f needed.
__global__ __launch_bounds__(256, 2) void k2(const float* __restrict__ xt,
                                             const float* __restrict__ Ja,
                                             float* __restrict__ ws) {
  __shared__ __align__(16) float Aw[G2R * 64];   // flat [k][64]; reused as red (w=1)
  __shared__ __align__(16) float Ae[G2R * 64];   // reused as red (w=2)
  __shared__ __align__(16) float2 Bvj[G2R][16];  // reused as red (w=3)
  const int tid = threadIdx.x;
  const int p0 = blockIdx.x * 16;
  const int cid = blockIdx.y;
  const int k0 = cid * G2R;
  const int validp = (NP - p0 < 16) ? (NP - p0) : 16;
  const int w = tid >> 6;
  const int lane = tid & 63;
  const int mg = lane & 15;   // m-quad: m = 4*mg .. +3
  const int pg = lane >> 4;   // p-quad: p = p0 + 4*pg .. +3

  // stage A: contiguous memcpy of wT/eT rows k0..k0+107 (tail rows pre-zeroed)
  {
    const float4* aws = (const float4*)(ws + OFF_WT + (size_t)k0 * 64);
    const float4* aes = (const float4*)(ws + OFF_ET + (size_t)k0 * 64);
    float4* aw4 = (float4*)Aw;
    float4* ae4 = (float4*)Ae;
    for (int idx = tid; idx < G2R * 16; idx += 256) { aw4[idx] = aws[idx]; ae4[idx] = aes[idx]; }
  }
  // stage B: (xt,Ja) interleaved [k][p-local]
  for (int idx = tid; idx < G2R * 4; idx += 256) {
    const int k = idx >> 2;
    const int pq = (idx & 3) * 4;
    const int t = k0 + k;
    float4 v = make_float4(0.f, 0.f, 0.f, 0.f), j = v;
    if (pq < validp && t < NT) {
      v = *(const float4*)(xt + (size_t)t * NP + p0 + pq);
      j = *(const float4*)(Ja + (size_t)t * NP + p0 + pq);
    }
    *(float4*)&Bvj[k][pq]     = make_float4(v.x, j.x, v.y, j.y);
    *(float4*)&Bvj[k][pq + 2] = make_float4(v.z, j.z, v.w, j.w);
  }
  __syncthreads();

  float f1[4][4] = {{0.f}}, f2[4][4] = {{0.f}};
  const float* AwL = Aw + 4 * mg;
  const float* AeL = Ae + 4 * mg;
  const int kb = w * 27;
  const int ke = kb + 27;
#pragma unroll 3
  for (int k = kb; k < ke; ++k) {
    const float4 aw = *(const float4*)(AwL + (size_t)k * 64);
    const float4 ae = *(const float4*)(AeL + (size_t)k * 64);
    const float4 b01 = *(const float4*)&Bvj[k][4 * pg];
    const float4 b23 = *(const float4*)&Bvj[k][4 * pg + 2];
    const float vb[4] = {b01.x, b01.z, b23.x, b23.z};
    const float jb[4] = {b01.y, b01.w, b23.y, b23.w};
    const float aww[4] = {aw.x, aw.y, aw.z, aw.w};
    const float aee[4] = {ae.x, ae.y, ae.z, ae.w};
#pragma unroll
    for (int mi = 0; mi < 4; mi++)
#pragma unroll
      for (int pj = 0; pj < 4; pj++) {
        f1[mi][pj] = fmaf(aww[mi], vb[pj], f1[mi][pj]);
        f2[mi][pj] = fmaf(aee[mi], jb[pj], f2[mi][pj]);
      }
  }
  __syncthreads();   // all waves done reading Aw/Ae/Bvj

  if (w > 0) {
    float* red = (w == 1) ? Aw : (w == 2) ? Ae : (float*)&Bvj[0][0];  // each >= 2048 floats
#pragma unroll
    for (int mi = 0; mi < 4; mi++)
#pragma unroll
      for (int pj = 0; pj < 4; pj++) {
        red[(mi * 4 + pj) * 64 + lane]      = f1[mi][pj];
        red[(16 + mi * 4 + pj) * 64 + lane] = f2[mi][pj];
      }
  }
  __syncthreads();
  if (w == 0) {
    const float* reds[3] = {Aw, Ae, (const float*)&Bvj[0][0]};
#pragma unroll
    for (int ww = 0; ww < 3; ww++) {
      const float* red = reds[ww];
#pragma unroll
      for (int mi = 0; mi < 4; mi++)
#pragma unroll
        for (int pj = 0; pj < 4; pj++) {
          f1[mi][pj] += red[(mi * 4 + pj) * 64 + lane];
          f2[mi][pj] += red[(16 + mi * 4 + pj) * 64 + lane];
        }
    }
    float* b1 = ws + OFF_SLAB + (size_t)(cid * 2 + 0) * NP * 64;
    float* b2 = ws + OFF_SLAB + (size_t)(cid * 2 + 1) * NP * 64;
#pragma unroll
    for (int pj = 0; pj < 4; pj++) {
      const int pl = 4 * pg + pj;
      if (pl < validp) {
        const int p = p0 + pl;
        *(float4*)(b1 + (size_t)p * 64 + 4 * mg) =
            make_float4(f1[0][pj], f1[1][pj], f1[2][pj], f1[3][pj]);
        *(float4*)(b2 + (size_t)p * 64 + 4 * mg) =
            make_float4(f2[0][pj], f2[1][pj], f2[2][pj], f2[3][pj]);
      }
    }
  }
}

// ---------- kernel 2.5: slab reduce, fully coalesced, thread-per-output ----------
__global__ __launch_bounds__(256) void k_red(float* __restrict__ ws) {
  const int inner = blockIdx.x * 256 + threadIdx.x;   // 138*256 = 35328 exactly
  const float* src = ws + OFF_SLAB + inner;
  float s = 0.f;
#pragma unroll 4
  for (int cid = 0; cid < G2S; cid++) s += src[(size_t)cid * SLABSTRIDE];
  ws[OFF_F + inner] = s;
}

// ---------- kernel 3: finalize (Es, forces) ----------
__global__ __launch_bounds__(320) void k3(const float* __restrict__ Rs,
                                          const float* __restrict__ ws,
                                          float* __restrict__ out) {
  const int m = blockIdx.x;
  const int tid = threadIdx.x;
  __shared__ float fx[NP];
  __shared__ float sR[NA * 3];
  __shared__ float sEsw[5], sSww[5];
  __shared__ float sTot[2];
  if (tid < NA * 3) sR[tid] = Rs[m * NA * 3 + tid];

  float aE = 0.f, aS = 0.f;
  for (int tt = tid; tt < 375; tt += 320) {
    aE += ws[OFF_ESP + (size_t)tt * 64 + m];
    aS += ws[OFF_SWP + (size_t)tt * 64 + m];
  }
#pragma unroll
  for (int off = 32; off; off >>= 1) {
    aE += __shfl_down(aE, off);
    aS += __shfl_down(aS, off);
  }
  if ((tid & 63) == 0) { sEsw[tid >> 6] = aE; sSww[tid >> 6] = aS; }
  __syncthreads();
  if (tid == 0) {
    float e = 0.f, s = 0.f;
#pragma unroll
    for (int w = 0; w < 5; w++) { e += sEsw[w]; s += sSww[w]; }
    sTot[0] = e; sTot[1] = s;
    out[m] = e / QC;  // *STD + C, STD=1, C=0
  }
  __syncthreads();
  const float sw = sTot[1];

  for (int p = tid; p < NP; p += 320) {
    const float f1p = ws[OFF_F + (size_t)0 * NP * 64 + p * 64 + m];
    const float f2  = ws[OFF_F + (size_t)1 * NP * 64 + p * 64 + m];
    const float u = ws[OFF_XS2 + (size_t)(m >> 5) * NP * 32 + p * 32 + (m & 31)];
    const float F1 = QC * (u * sw - f1p);
    fx[p] = (F1 - f2) * u * u * u;
  }
  __syncthreads();

  if (tid < NA * 3) {
    const int a = tid / 3, cc = tid % 3;
    const float ra = sR[a * 3 + cc];
    float acc = 0.f;
    for (int b = 0; b < NA; b++) {
      if (b == a) continue;
      const int i = a > b ? a : b, j = a > b ? b : a;
      const int p = i * (i - 1) / 2 + j;
      acc += (sR[b * 3 + cc] - ra) * fx[p];
    }
    out[MM + m * NA * 3 + tid] = acc;
  }
}

extern "C" void kernel_launch(void* const* d_in, const int* in_sizes, int n_in,
                              void* d_out, int out_size, void* d_ws, size_t ws_size,
                              hipStream_t stream) {
  const float* Rs = (const float*)d_in[0];
  const float* xt = (const float*)d_in[1];
  const float* Ja = (const float*)d_in[2];
  float* out = (float*)d_out;
  float* ws = (float*)d_ws;

  k_pre<<<MM, 256, 0, stream>>>(Rs, ws);
  k1<<<dim3(375, 2), 256, 0, stream>>>(xt, Ja, ws);
  k2<<<dim3(18, G2S), 256, 0, stream>>>(xt, Ja, ws);
  k_red<<<138, 256, 0, stream>>>(ws);
  k3<<<MM, 320, 0, stream>>>(Rs, ws, out);
}

// Round 8
// 117.216 us; speedup vs baseline: 1.0629x; 1.0100x over previous
//
#include <hip/hip_runtime.h>
#include <math.h>

#define MM 64
#define NA 24
#define NP 276
#define NT 6000
#define QC 0.22360679774997896f
#define EXPC 0.01666666666666667f  // 5/(3*sig^2), sig=10

// k2 tiles: 6048 = 56 chunks x 108 k, single staging round per block
#define G2S   56
#define G2R   108

// ---- workspace layout (float offsets) ----
#define OFF_WT   0           // wT[t][m] 6048*64 (rows 6000..6047 zeroed by k_pre)
#define OFF_ET   387072      // eT[t][m] 6048*64
#define OFF_SLAB 774144      // slab[cid][mat][p][m] 56*2*276*64 (k2 partials)
#define OFF_ESP  2752512     // esP[tile][m] 375*64
#define OFF_SWP  2776512     // swP[tile][m] 375*64
#define OFF_XS2  2800512     // xsT2[half][p][ml] 2*276*32
#define OFF_UU   2818176     // 64
#define OFF_VV   2818240     // 6000
#define OFF_C1   2824240     // 6000
#define OFF_F    2830240     // F[mat][p][m] 2*276*64 (k_red output)
#define SLABSTRIDE 35328     // 2*276*64

__device__ __forceinline__ void p2ij(int p, int& i, int& j) {
  int ii = (int)((1.0f + sqrtf(1.0f + 8.0f * (float)p)) * 0.5f);
  while (ii * (ii - 1) / 2 > p) ii--;
  while ((ii + 1) * ii / 2 <= p) ii++;
  j = p - ii * (ii - 1) / 2;
  i = ii;
}

// ---------- kernel 0: xsT2 + uu (blocks 0..63), vv/c1 stats (blocks 64..1563) ----------
__global__ __launch_bounds__(256) void k_pre(const float* __restrict__ Rs,
                                             const float* __restrict__ xt,
                                             const float* __restrict__ Ja,
                                             float* __restrict__ ws) {
  const int tid = threadIdx.x;
  const int bid = blockIdx.x;
  if (bid < MM) {
    if (bid < 2) {
      float* tz = ws + (bid ? OFF_ET : OFF_WT) + (size_t)NT * 64;
      for (int z = tid; z < 48 * 64; z += 256) tz[z] = 0.f;
    }
    const int m = bid;
    __shared__ float sR[NA * 3];
    __shared__ float sAcc[4];
    if (tid < NA * 3) sR[tid] = Rs[m * NA * 3 + tid];
    __syncthreads();
    float acc = 0.f;
    for (int p = tid; p < NP; p += 256) {
      int i, j;
      p2ij(p, i, j);
      const float dx = sR[i * 3 + 0] - sR[j * 3 + 0];
      const float dy = sR[i * 3 + 1] - sR[j * 3 + 1];
      const float dz = sR[i * 3 + 2] - sR[j * 3 + 2];
      const float u = 1.0f / sqrtf(dx * dx + dy * dy + dz * dz);
      ws[OFF_XS2 + (size_t)(m >> 5) * NP * 32 + p * 32 + (m & 31)] = u;
      acc = fmaf(u, u, acc);
    }
#pragma unroll
    for (int off = 32; off; off >>= 1) acc += __shfl_down(acc, off);
    if ((tid & 63) == 0) sAcc[tid >> 6] = acc;
    __syncthreads();
    if (tid == 0) ws[OFF_UU + m] = sAcc[0] + sAcc[1] + sAcc[2] + sAcc[3];
  } else {
    // stats: vv[t] = sum_k xt[t][k]^2, c1[t] = sum_k xt[t][k]*Ja[t][k]
    const int sb = bid - MM;                 // 0..1499
    const int t = sb * 4 + (tid >> 6);       // 4 t-rows per block
    const int lane = tid & 63;
    const float* xr = xt + (size_t)t * NP;
    const float* jr = Ja + (size_t)t * NP;
    float a = 0.f, b = 0.f;
#pragma unroll
    for (int q = 0; q < 4; q++) {
      const float v = xr[lane + 64 * q];
      const float jj = jr[lane + 64 * q];
      a = fmaf(v, v, a);
      b = fmaf(v, jj, b);
    }
    if (lane < NP - 256) {
      const float v = xr[256 + lane];
      const float jj = jr[256 + lane];
      a = fmaf(v, v, a);
      b = fmaf(v, jj, b);
    }
#pragma unroll
    for (int off = 32; off; off >>= 1) {
      a += __shfl_down(a, off);
      b += __shfl_down(b, off);
    }
    if (lane == 0) { ws[OFF_VV + t] = a; ws[OFF_C1 + t] = b; }
  }
}

// ---------- kernel 1: GEMM1, 4-way K-split, thread tile 4m x 2t (2 B/FMA) ----------
// grid (375 t-tiles, 2 m-halves); block 256 = 4 waves.
// Wave w: k-range [68w, 68w+68) (wave 3: +72). Lane: mg=lane&7 (4m), tg=lane>>3 (2t).
// Cross-wave reduce via LDS (reusing As region), wave 0 does epilogue.
#define K1SUB(A, vb0, vb1, jb0, jb1)                                               \
  av0[0] = fmaf(A.x, vb0, av0[0]); av0[1] = fmaf(A.y, vb0, av0[1]);                \
  av0[2] = fmaf(A.z, vb0, av0[2]); av0[3] = fmaf(A.w, vb0, av0[3]);                \
  av1[0] = fmaf(A.x, vb1, av1[0]); av1[1] = fmaf(A.y, vb1, av1[1]);                \
  av1[2] = fmaf(A.z, vb1, av1[2]); av1[3] = fmaf(A.w, vb1, av1[3]);                \
  aj0[0] = fmaf(A.x, jb0, aj0[0]); aj0[1] = fmaf(A.y, jb0, aj0[1]);                \
  aj0[2] = fmaf(A.z, jb0, aj0[2]); aj0[3] = fmaf(A.w, jb0, aj0[3]);                \
  aj1[0] = fmaf(A.x, jb1, aj1[0]); aj1[1] = fmaf(A.y, jb1, aj1[1]);                \
  aj1[2] = fmaf(A.z, jb1, aj1[2]); aj1[3] = fmaf(A.w, jb1, aj1[3]);

__global__ __launch_bounds__(256, 2) void k1(const float* __restrict__ xt,
                                             const float* __restrict__ Ja,
                                             float* __restrict__ ws) {
  __shared__ __align__(16) float Bv[16 * NP];   // flat copy of xt tile
  __shared__ __align__(16) float Bj[16 * NP];   // flat copy of Ja tile
  __shared__ __align__(16) float As[NP * 32];   // xsT2 half [p][ml]; reused as red[3][16][64]
  const int tid = threadIdx.x;
  const int t0 = blockIdx.x * 16;
  const int m0 = blockIdx.y * 32;
  const int w = tid >> 6;
  const int lane = tid & 63;
  const int mg = lane & 7;     // m-quad: m = m0 + 4*mg .. +3
  const int tg = lane >> 3;    // t-pair: t = t0 + 2*tg + {0,1}

  // epilogue params (only wave 0 uses; load early for latency)
  const float4 uu4 = *(const float4*)(ws + OFF_UU + m0 + 4 * mg);
  const float2 vv2 = *(const float2*)(ws + OFF_VV + t0 + 2 * tg);
  const float2 c12 = *(const float2*)(ws + OFF_C1 + t0 + 2 * tg);

  // stage: pure linear float4 copies
  {
    const float4* xs4 = (const float4*)(xt + (size_t)t0 * NP);
    const float4* js4 = (const float4*)(Ja + (size_t)t0 * NP);
    const float4* as4 = (const float4*)(ws + OFF_XS2 + (size_t)blockIdx.y * NP * 32);
    float4* bv4 = (float4*)Bv;
    float4* bj4 = (float4*)Bj;
    float4* a4  = (float4*)As;
    for (int i = tid; i < 16 * NP / 4; i += 256) { bv4[i] = xs4[i]; bj4[i] = js4[i]; }
    for (int i = tid; i < NP * 32 / 4; i += 256) a4[i] = as4[i];
  }
  __syncthreads();

  float av0[4] = {0.f, 0.f, 0.f, 0.f}, av1[4] = {0.f, 0.f, 0.f, 0.f};
  float aj0[4] = {0.f, 0.f, 0.f, 0.f}, aj1[4] = {0.f, 0.f, 0.f, 0.f};
  const float* BvR0 = Bv + (2 * tg + 0) * NP;
  const float* BvR1 = Bv + (2 * tg + 1) * NP;
  const float* BjR0 = Bj + (2 * tg + 0) * NP;
  const float* BjR1 = Bj + (2 * tg + 1) * NP;
  const float* Ac = As + 4 * mg;
  const int kbeg = w * 68;
  const int kend = (w == 3) ? NP : (kbeg + 68);
#pragma unroll 2
  for (int k = kbeg; k < kend; k += 4) {
    const float4 a0 = *(const float4*)(Ac + (k + 0) * 32);
    const float4 a1 = *(const float4*)(Ac + (k + 1) * 32);
    const float4 a2 = *(const float4*)(Ac + (k + 2) * 32);
    const float4 a3 = *(const float4*)(Ac + (k + 3) * 32);
    const float4 bv0 = *(const float4*)(BvR0 + k);
    const float4 bv1 = *(const float4*)(BvR1 + k);
    const float4 bj0 = *(const float4*)(BjR0 + k);
    const float4 bj1 = *(const float4*)(BjR1 + k);
    K1SUB(a0, bv0.x, bv1.x, bj0.x, bj1.x)
    K1SUB(a1, bv0.y, bv1.y, bj0.y, bj1.y)
    K1SUB(a2, bv0.z, bv1.z, bj0.z, bj1.z)
    K1SUB(a3, bv0.w, bv1.w, bj0.w, bj1.w)
  }
  __syncthreads();   // all waves done reading As/Bv/Bj

  if (w > 0) {
    float* red = As + (size_t)(w - 1) * 16 * 64;
#pragma unroll
    for (int q = 0; q < 4; q++) {
      red[(q + 0) * 64 + lane]  = av0[q];
      red[(q + 4) * 64 + lane]  = av1[q];
      red[(q + 8) * 64 + lane]  = aj0[q];
      red[(q + 12) * 64 + lane] = aj1[q];
    }
  }
  __syncthreads();
  if (w == 0) {
#pragma unroll
    for (int ww = 0; ww < 3; ww++) {
      const float* red = As + (size_t)ww * 16 * 64;
#pragma unroll
      for (int q = 0; q < 4; q++) {
        av0[q] += red[(q + 0) * 64 + lane];
        av1[q] += red[(q + 4) * 64 + lane];
        aj0[q] += red[(q + 8) * 64 + lane];
        aj1[q] += red[(q + 12) * 64 + lane];
      }
    }
    float es[4] = {0.f, 0.f, 0.f, 0.f}, swv[4] = {0.f, 0.f, 0.f, 0.f};
    const float uum[4] = {uu4.x, uu4.y, uu4.z, uu4.w};
#pragma unroll
    for (int tj = 0; tj < 2; tj++) {
      const float vvt = tj ? vv2.y : vv2.x;
      const float c1t = tj ? c12.y : c12.x;
      const float* g1 = tj ? av1 : av0;
      const float* g2 = tj ? aj1 : aj0;
      float wq[4], eq[4];
#pragma unroll
      for (int mi = 0; mi < 4; mi++) {
        const float d2 = fmaxf(uum[mi] - 2.f * g1[mi] + vvt, 0.f);
        const float xd = QC * sqrtf(d2);
        const float dv = QC * (g2[mi] - c1t);
        const float ex = EXPC * __expf(-xd);
        const float e1v = ex * (1.f + xd);
        const float w_ = ex * dv;
        wq[mi] = w_; eq[mi] = e1v;
        es[mi] += e1v * dv; swv[mi] += w_;
      }
      const int t = t0 + 2 * tg + tj;
      *(float4*)(ws + OFF_WT + (size_t)t * 64 + m0 + 4 * mg) = make_float4(wq[0], wq[1], wq[2], wq[3]);
      *(float4*)(ws + OFF_ET + (size_t)t * 64 + m0 + 4 * mg) = make_float4(eq[0], eq[1], eq[2], eq[3]);
    }
    // reduce es/sw over the 8 t-groups (lane bits 3..5)
#pragma unroll
    for (int q = 0; q < 4; q++) {
      es[q] += __shfl_down(es[q], 32); es[q] += __shfl_down(es[q], 16); es[q] += __shfl_down(es[q], 8);
      swv[q] += __shfl_down(swv[q], 32); swv[q] += __shfl_down(swv[q], 16); swv[q] += __shfl_down(swv[q], 8);
    }
    if (lane < 8) {
      *(float4*)(ws + OFF_ESP + (size_t)blockIdx.x * 64 + m0 + 4 * lane) =
          make_float4(es[0], es[1], es[2], es[3]);
      *(float4*)(ws + OFF_SWP + (size_t)blockIdx.x * 64 + m0 + 4 * lane) =
          make_float4(swv[0], swv[1], swv[2], swv[3]);
    }
  }
}

// ---------- kernel 2: GEMM2, 4-way K-split, thread tile 4m x 4p (2 B/FMA) ----------
// grid (18 p-tiles x 56 k-chunks); block 256 = 4 waves.
// Wave w: k-range [27w, 27w+27). Lane: mg=lane&15 (4m), pg=lane>>4 (4p).
__global__ __launch_bounds__(256, 2) void k2(const float* __restrict__ xt,
                                             const float* __restrict__ Ja,
                                             float* __restrict__ ws) {
  __shared__ __align__(16) float Aw[G2R * 64];   // flat [k][64]; reused as red (w=1)
  __shared__ __align__(16) float Ae[G2R * 64];   // reused as red (w=2)
  __shared__ __align__(16) float2 Bvj[G2R][16];  // (v,j) interleaved; reused as red (w=3)
  const int tid = threadIdx.x;
  const int p0 = blockIdx.x * 16;
  const int cid = blockIdx.y;
  const int k0 = cid * G2R;
  const int validp = (NP - p0 < 16) ? (NP - p0) : 16;
  const int w = tid >> 6;
  const int lane = tid & 63;
  const int mg = lane & 15;   // m-quad: m = 4*mg .. +3
  const int pg = lane >> 4;   // p-quad: p = p0 + 4*pg .. +3

  // stage A: contiguous memcpy of wT/eT rows k0..k0+107 (tail rows pre-zeroed)
  {
    const float4* aws = (const float4*)(ws + OFF_WT + (size_t)k0 * 64);
    const float4* aes = (const float4*)(ws + OFF_ET + (size_t)k0 * 64);
    float4* aw4 = (float4*)Aw;
    float4* ae4 = (float4*)Ae;
    for (int idx = tid; idx < G2R * 16; idx += 256) { aw4[idx] = aws[idx]; ae4[idx] = aes[idx]; }
  }
  // stage B: (xt,Ja) interleaved [k][p-local]
  for (int idx = tid; idx < G2R * 4; idx += 256) {
    const int k = idx >> 2;
    const int pq = (idx & 3) * 4;
    const int t = k0 + k;
    float4 v = make_float4(0.f, 0.f, 0.f, 0.f), j = v;
    if (pq < validp && t < NT) {
      v = *(const float4*)(xt + (size_t)t * NP + p0 + pq);
      j = *(const float4*)(Ja + (size_t)t * NP + p0 + pq);
    }
    *(float4*)&Bvj[k][pq]     = make_float4(v.x, j.x, v.y, j.y);
    *(float4*)&Bvj[k][pq + 2] = make_float4(v.z, j.z, v.w, j.w);
  }
  __syncthreads();

  float f1[4][4] = {{0.f}}, f2[4][4] = {{0.f}};
  const float* AwL = Aw + 4 * mg;
  const float* AeL = Ae + 4 * mg;
  const int kb = w * 27;
  const int ke = kb + 27;
#pragma unroll 3
  for (int k = kb; k < ke; ++k) {
    const float4 aw = *(const float4*)(AwL + (size_t)k * 64);
    const float4 ae = *(const float4*)(AeL + (size_t)k * 64);
    const float4 b01 = *(const float4*)&Bvj[k][4 * pg];
    const float4 b23 = *(const float4*)&Bvj[k][4 * pg + 2];
    const float vb[4] = {b01.x, b01.z, b23.x, b23.z};
    const float jb[4] = {b01.y, b01.w, b23.y, b23.w};
    const float aww[4] = {aw.x, aw.y, aw.z, aw.w};
    const float aee[4] = {ae.x, ae.y, ae.z, ae.w};
#pragma unroll
    for (int mi = 0; mi < 4; mi++)
#pragma unroll
      for (int pj = 0; pj < 4; pj++) {
        f1[mi][pj] = fmaf(aww[mi], vb[pj], f1[mi][pj]);
        f2[mi][pj] = fmaf(aee[mi], jb[pj], f2[mi][pj]);
      }
  }
  __syncthreads();   // all waves done reading Aw/Ae/Bvj

  if (w > 0) {
    float* red = (w == 1) ? Aw : (w == 2) ? Ae : (float*)&Bvj[0][0];  // each >= 2048 floats
#pragma unroll
    for (int mi = 0; mi < 4; mi++)
#pragma unroll
      for (int pj = 0; pj < 4; pj++) {
        red[(mi * 4 + pj) * 64 + lane]      = f1[mi][pj];
        red[(16 + mi * 4 + pj) * 64 + lane] = f2[mi][pj];
      }
  }
  __syncthreads();
  if (w == 0) {
    const float* reds[3] = {Aw, Ae, (const float*)&Bvj[0][0]};
#pragma unroll
    for (int ww = 0; ww < 3; ww++) {
      const float* red = reds[ww];
#pragma unroll
      for (int mi = 0; mi < 4; mi++)
#pragma unroll
        for (int pj = 0; pj < 4; pj++) {
          f1[mi][pj] += red[(mi * 4 + pj) * 64 + lane];
          f2[mi][pj] += red[(16 + mi * 4 + pj) * 64 + lane];
        }
    }
    float* b1 = ws + OFF_SLAB + (size_t)(cid * 2 + 0) * NP * 64;
    float* b2 = ws + OFF_SLAB + (size_t)(cid * 2 + 1) * NP * 64;
#pragma unroll
    for (int pj = 0; pj < 4; pj++) {
      const int pl = 4 * pg + pj;
      if (pl < validp) {
        const int p = p0 + pl;
        *(float4*)(b1 + (size_t)p * 64 + 4 * mg) =
            make_float4(f1[0][pj], f1[1][pj], f1[2][pj], f1[3][pj]);
        *(float4*)(b2 + (size_t)p * 64 + 4 * mg) =
            make_float4(f2[0][pj], f2[1][pj], f2[2][pj], f2[3][pj]);
      }
    }
  }
}

// ---------- kernel 2.5: slab reduce, fully coalesced, thread-per-output ----------
__global__ __launch_bounds__(256) void k_red(float* __restrict__ ws) {
  const int inner = blockIdx.x * 256 + threadIdx.x;   // 138*256 = 35328 exactly
  const float* src = ws + OFF_SLAB + inner;
  float s = 0.f;
#pragma unroll 4
  for (int cid = 0; cid < G2S; cid++) s += src[(size_t)cid * SLABSTRIDE];
  ws[OFF_F + inner] = s;
}

// ---------- kernel 3: finalize (Es, forces) ----------
__global__ __launch_bounds__(320) void k3(const float* __restrict__ Rs,
                                          const float* __restrict__ ws,
                                          float* __restrict__ out) {
  const int m = blockIdx.x;
  const int tid = threadIdx.x;
  __shared__ float fx[NP];
  __shared__ float sR[NA * 3];
  __shared__ float sEsw[5], sSww[5];
  __shared__ float sTot[2];
  if (tid < NA * 3) sR[tid] = Rs[m * NA * 3 + tid];

  float aE = 0.f, aS = 0.f;
  for (int tt = tid; tt < 375; tt += 320) {
    aE += ws[OFF_ESP + (size_t)tt * 64 + m];
    aS += ws[OFF_SWP + (size_t)tt * 64 + m];
  }
#pragma unroll
  for (int off = 32; off; off >>= 1) {
    aE += __shfl_down(aE, off);
    aS += __shfl_down(aS, off);
  }
  if ((tid & 63) == 0) { sEsw[tid >> 6] = aE; sSww[tid >> 6] = aS; }
  __syncthreads();
  if (tid == 0) {
    float e = 0.f, s = 0.f;
#pragma unroll
    for (int w = 0; w < 5; w++) { e += sEsw[w]; s += sSww[w]; }
    sTot[0] = e; sTot[1] = s;
    out[m] = e / QC;  // *STD + C, STD=1, C=0
  }
  __syncthreads();
  const float sw = sTot[1];

  for (int p = tid; p < NP; p += 320) {
    const float f1p = ws[OFF_F + (size_t)0 * NP * 64 + p * 64 + m];
    const float f2  = ws[OFF_F + (size_t)1 * NP * 64 + p * 64 + m];
    const float u = ws[OFF_XS2 + (size_t)(m >> 5) * NP * 32 + p * 32 + (m & 31)];
    const float F1 = QC * (u * sw - f1p);
    fx[p] = (F1 - f2) * u * u * u;
  }
  __syncthreads();

  if (tid < NA * 3) {
    const int a = tid / 3, cc = tid % 3;
    const float ra = sR[a * 3 + cc];
    float acc = 0.f;
    for (int b = 0; b < NA; b++) {
      if (b == a) continue;
      const int i = a > b ? a : b, j = a > b ? b : a;
      const int p = i * (i - 1) / 2 + j;
      acc += (sR[b * 3 + cc] - ra) * fx[p];
    }
    out[MM + m * NA * 3 + tid] = acc;
  }
}

extern "C" void kernel_launch(void* const* d_in, const int* in_sizes, int n_in,
                              void* d_out, int out_size, void* d_ws, size_t ws_size,
                              hipStream_t stream) {
  const float* Rs = (const float*)d_in[0];
  const float* xt = (const float*)d_in[1];
  const float* Ja = (const float*)d_in[2];
  float* out = (float*)d_out;
  float* ws = (float*)d_ws;

  k_pre<<<MM + 1500, 256, 0, stream>>>(Rs, xt, Ja, ws);
  k1<<<dim3(375, 2), 256, 0, stream>>>(xt, Ja, ws);
  k2<<<dim3(18, G2S), 256, 0, stream>>>(xt, Ja, ws);
  k_red<<<138, 256, 0, stream>>>(ws);
  k3<<<MM, 320, 0, stream>>>(Rs, ws, out);
}